// Round 1
// baseline (148.992 us; speedup 1.0000x reference)
//
#include <hip/hip_runtime.h>

// Shapes (compile-time constants per the reference):
// J=64 inputs, T=64 terms/input, NV=4 vars, K=8 coeffs, I=64 output nodes.
// under/over: [I, 2*J*T+1, NV, K] fp32 ; degrees: [I, NV] each.
namespace {
constexpr int Jc = 64, Tc = 64, NVc = 4, Kc = 8, Ic = 64;
constexpr int F4_TERM  = (NVc * Kc) / 4;          // 8 float4 per term (32 floats)
constexpr int TERMS    = 2 * Jc * Tc + 1;         // 8193 terms per node
constexpr int NODE_F4  = TERMS * F4_TERM;         // 65544 float4 per node
constexpr int HALF_F4  = Jc * Tc * F4_TERM;       // 32768 float4 per half
constexpr int TILE_F4  = Tc * F4_TERM;            // 512 float4 per input-j tile
constexpr long long OVER_BASE_F4 = (long long)Ic * NODE_F4;   // 4,194,816
constexpr long long DEG_BASE_FLT = 2LL * OVER_BASE_F4 * 4;    // 33,558,528 floats
}

__device__ __forceinline__ float4 scale4(float4 v, float s) {
    return make_float4(v.x * s, v.y * s, v.z * s, v.w * s);
}

__global__ __launch_bounds__(256) void layer_kernel(
    const float4* __restrict__ liu,   // layer_inputs_under  [J,T,NV,K]
    const float4* __restrict__ lio,   // layer_inputs_over   [J,T,NV,K]
    const float*  __restrict__ ud,    // under degrees [J,NV]
    const float*  __restrict__ od,    // over degrees  [J,NV]
    const float*  __restrict__ w,     // weights [I,J]
    const float*  __restrict__ bias,  // biases [I]
    float*        __restrict__ outf)  // under || over || under_deg || over_deg
{
    float4* out = reinterpret_cast<float4*>(outf);
    const int b = blockIdx.x;

    if (b < Ic * Jc) {
        const int i = b >> 6;
        const int j = b & 63;
        const float wv = w[i * Jc + j];
        const float wp = fmaxf(wv, 0.0f);   // relu(w)
        const float wn = fminf(wv, 0.0f);   // -relu(-w)

        const float4* liot = lio + j * TILE_F4;
        const float4* liut = liu + j * TILE_F4;
        float4* u_a = out + (long long)i * NODE_F4 + j * TILE_F4; // under: lio*wn half
        float4* u_b = u_a + HALF_F4;                              // under: liu*wp half
        float4* o_a = u_a + OVER_BASE_F4;                         // over:  lio*wp half
        float4* o_b = o_a + HALF_F4;                              // over:  liu*wn half

        #pragma unroll
        for (int r = 0; r < 2; ++r) {
            const int idx = r * 256 + (int)threadIdx.x;  // [0, 512)
            const float4 a = liot[idx];
            const float4 c = liut[idx];
            // var index = (idx & 7) >> 1 ; var 0 rows are float4 slots 0,1 of each term
            const bool v0 = (idx & 7) < 2;
            const float sn = v0 ? wn : 1.0f;
            const float sp = v0 ? wp : 1.0f;
            u_a[idx] = scale4(a, sn);
            u_b[idx] = scale4(c, sp);
            o_a[idx] = scale4(a, sp);
            o_b[idx] = scale4(c, sn);
        }
    } else {
        // Tail block: bias/ones terms (term index 2*J*T) for all nodes + degrees.
        const int tid = (int)threadIdx.x;
        #pragma unroll
        for (int r = 0; r < 2; ++r) {
            const int idx  = r * 256 + tid;   // [0, 512) = 64 nodes * 8 float4
            const int node = idx >> 3;
            const int sub  = idx & 7;         // float4 slot within term; var = sub>>1
            const float val = (sub < 2) ? bias[node] : 1.0f;  // var0 row = bias, rest = 1
            const float4 v = make_float4(val, val, val, val);
            const long long off = (long long)node * NODE_F4 +
                                  (long long)(2 * Jc * Tc) * F4_TERM + sub;
            out[off] = v;
            out[off + OVER_BASE_F4] = v;
        }
        // degrees: deg[var] = max_j max(ud[j,var], od[j,var]); broadcast to [I,NV].
        const int var = tid & 3;
        float m = -3.4e38f;
        for (int j = 0; j < Jc; ++j) {
            m = fmaxf(m, fmaxf(ud[j * NVc + var], od[j * NVc + var]));
        }
        outf[DEG_BASE_FLT + tid] = m;          // under_deg, tid = i*4+var
        outf[DEG_BASE_FLT + 256 + tid] = m;    // over_deg
    }
}

extern "C" void kernel_launch(void* const* d_in, const int* in_sizes, int n_in,
                              void* d_out, int out_size, void* d_ws, size_t ws_size,
                              hipStream_t stream) {
    const float4* liu  = (const float4*)d_in[0];
    const float4* lio  = (const float4*)d_in[1];
    const float*  ud   = (const float*)d_in[2];
    const float*  od   = (const float*)d_in[3];
    const float*  w    = (const float*)d_in[4];
    const float*  bias = (const float*)d_in[5];
    float* outf = (float*)d_out;

    // 4096 blocks for (i,j) tiles + 1 tail block for bias terms and degrees.
    layer_kernel<<<dim3(Ic * Jc + 1), dim3(256), 0, stream>>>(
        liu, lio, ud, od, w, bias, outf);
}